// Round 7
// baseline (58.518 us; speedup 1.0000x reference)
//
#include <hip/hip_runtime.h>

// ---------------------------------------------------------------------------
// Model_51453708206406: fast_pos_embed_interpolate + MRoPE cos/sin (f32 out).
// Outputs concatenated: [46080,1152] pe | [46080,128] cos | [46080,128] sin.
// Static grid: {1,64,64},{4,48,48},{8,32,64},{16,32,32}; merge m=2, G=35.
//
// v7: channel-chunk-major ordering. Patch blocks are grouped into 8 chunks of
// 36 channel-quads (144 ch); within a chunk all tokens of all images are
// processed against a 706 KB table slice (1225 pts x 144 ch) that stays
// L2-resident per XCD -> table reads stop costing fabric BW. Output stores
// remain non-temporal (bypass L2, don't evict the slice). Patch keeps
// frame-dedup (compute frame 0, replicate stores across T).
// ---------------------------------------------------------------------------

typedef float fx4 __attribute__((ext_vector_type(4)));

__device__ __forceinline__ void nt_store4(float* p, fx4 v) {
    __builtin_nontemporal_store(v, (fx4*)p);
}

// r: block index within (image, chunk); covers frame-0 tokens x 36 quads.
template <int T, int H, int W, int OFF>
__device__ __forceinline__ void patch_body(int r, int chunk,
                                           const float* __restrict__ tab,
                                           float* __restrict__ out) {
    constexpr int HW = H * W;
    constexpr int WB = W / 2;

    int idx = r * 256 + (int)threadIdx.x; // < HW_frame0 * 36 (mult of 256)
    int tok = idx / 36;                   // frame-0 token in merged order
    int c4w = idx - tok * 36;
    int c4  = chunk * 36 + c4w;           // global channel-quad in [0,288)

    // invert merged-block ordering: tok = ((bh*WB+bw)<<2)+(i<<1)+j
    int j  = tok & 1;
    int i  = (tok >> 1) & 1;
    int blk = tok >> 2;
    int bw = blk % WB;
    int bh = blk / WB;
    int row = (bh << 1) + i;
    int col = (bw << 1) + j;

    // linspace(0,34,H)[row], linspace(0,34,W)[col]
    float hx = (float)row * (float)(34.0 / (H - 1));
    float wx = (float)col * (float)(34.0 / (W - 1));
    int hf = (int)hx, wf = (int)wx;
    float dh = hx - (float)hf, dw = wx - (float)wf;
    int hc = min(hf + 1, 34), wc = min(wf + 1, 34);

    float w00 = (1.f - dh) * (1.f - dw);
    float w01 = (1.f - dh) * dw;
    float w10 = dh * (1.f - dw);
    float w11 = dh * dw;

    const fx4 a = *((const fx4*)(tab + (hf * 35 + wf) * 1152) + c4);
    const fx4 bq= *((const fx4*)(tab + (hf * 35 + wc) * 1152) + c4);
    const fx4 c = *((const fx4*)(tab + (hc * 35 + wf) * 1152) + c4);
    const fx4 d = *((const fx4*)(tab + (hc * 35 + wc) * 1152) + c4);

    fx4 o = w00 * a + w01 * bq + w10 * c + w11 * d;

    float* dst = out + (size_t)(OFF + tok) * 1152 + (c4 << 2);
    #pragma unroll
    for (int f = 0; f < T; ++f)           // frames are identical copies
        nt_store4(dst + (size_t)f * (HW * 1152), o);
}

// Fully frame-split rope: every thread -> one (token, channel-quad), 64B.
template <int T, int H, int W, int OFF>
__device__ __forceinline__ void rope_body(int b, const float* __restrict__ invf,
                                          float* __restrict__ cosO,
                                          float* __restrict__ sinO) {
    constexpr int HW = H * W;
    constexpr int WB = W / 2;

    int idx = b * 256 + (int)threadIdx.x; // < T*HW*16 (mult of 256)
    int tok = idx >> 4;                   // global token within this image
    int l4  = idx & 15;                   // channel-quad, d0 = 4*l4 in [0,64)
    int rem = tok % HW;                   // frame-local (frames identical)

    int j  = rem & 1;
    int i  = (rem >> 1) & 1;
    int blk = rem >> 2;
    int bw = blk % WB;
    int bh = blk / WB;
    int row = (bh << 1) + i;
    int col = (bw << 1) + j;

    float fp = (float)((l4 < 8) ? row : col);   // d0<32 -> row else col
    fx4 iv = ((const fx4*)invf)[l4 & 7];

    float s0, c0, s1, c1, s2, c2, s3, c3;
    __sincosf(fp * iv.x, &s0, &c0);
    __sincosf(fp * iv.y, &s1, &c1);
    __sincosf(fp * iv.z, &s2, &c2);
    __sincosf(fp * iv.w, &s3, &c3);
    fx4 cv = {c0, c1, c2, c3};
    fx4 sv = {s0, s1, s2, s3};

    size_t base = (size_t)(OFF + tok) * 128 + (l4 << 2);
    nt_store4(cosO + base,      cv);      // first 64-wide half
    nt_store4(cosO + base + 64, cv);      // duplicated half
    nt_store4(sinO + base,      sv);
    nt_store4(sinO + base + 64, sv);
}

// Patch: 8 chunks x 1332 blocks (img3 144 | img2 288 | img1 324 | img0 576),
// heavy-per-block first within each chunk. Then rope: 2880 blocks
// (img3 1024 | img2 1024 | img1 576 | img0 256). Total 13536.
__global__ __launch_bounds__(256) void fused_kernel(
    const float* __restrict__ tab, const float* __restrict__ invf,
    float* __restrict__ out, float* __restrict__ cosO, float* __restrict__ sinO)
{
    int b = (int)blockIdx.x;
    if (b < 10656) {
        int chunk = b / 1332;             // channel-chunk (36 quads)
        int r     = b - chunk * 1332;
        if      (r < 144) patch_body<16,32, 32, 29696>(r,       chunk, tab, out);
        else if (r < 432) patch_body<8, 32, 64, 13312>(r - 144, chunk, tab, out);
        else if (r < 756) patch_body<4, 48, 48, 4096> (r - 432, chunk, tab, out);
        else              patch_body<1, 64, 64, 0>    (r - 756, chunk, tab, out);
    } else {
        int r = b - 10656;
        if      (r < 1024) rope_body<16,32, 32, 29696>(r,        invf, cosO, sinO);
        else if (r < 2048) rope_body<8, 32, 64, 13312>(r - 1024, invf, cosO, sinO);
        else if (r < 2624) rope_body<4, 48, 48, 4096> (r - 2048, invf, cosO, sinO);
        else               rope_body<1, 64, 64, 0>    (r - 2624, invf, cosO, sinO);
    }
}

extern "C" void kernel_launch(void* const* d_in, const int* in_sizes, int n_in,
                              void* d_out, int out_size, void* d_ws, size_t ws_size,
                              hipStream_t stream) {
    const float* tab  = (const float*)d_in[1];   // [1225, 1152]
    const float* invf = (const float*)d_in[2];   // [32]
    float* out = (float*)d_out;

    constexpr size_t NTOK = 46080;
    float* cosO = out + NTOK * 1152;
    float* sinO = cosO + NTOK * 128;

    fused_kernel<<<13536, 256, 0, stream>>>(tab, invf, out, cosO, sinO);
}